// Round 5
// baseline (1604.949 us; speedup 1.0000x reference)
//
#include <hip/hip_runtime.h>

// ============================================================================
// TypeNet triplet embedder: 2x(LSTM + BatchNorm) + FC + L2norm, for a,p,n.
// Round 5: 96 WGs x 1024 thr (4 waves/SIMD TLP), wave-pair row-split
// elementwise, log2e-prescaled weights (exp2-native gates, 7 trans/elem),
// conflict-free A-frag LDS, fused prep kernels.
//  - Waves w and w+8 both own h-cols [16w,16w+16): both issue the MFMAs
//    (cheap, duplicated), elementwise split 2 rows each (issue-bound pipe).
//  - All gate pre-activations come out of MFMA already scaled by log2e
//    (2log2e for g-gate); cell state kept as cs = 2log2e*c.
//  - BAR = s_waitcnt lgkmcnt(0) + s_barrier (no vmcnt drain).
// ============================================================================

typedef __attribute__((ext_vector_type(8))) _Float16 half8;
typedef __attribute__((ext_vector_type(4))) float f32x4;

#define TS 128
#define HID 128
#define NGATE 512
#define INV_N (1.0f/65536.0f)   // 1/(B*T)
#define ONE_L 1.4426950408889634f
#define TWO_L 2.8853900817779268f

#define BAR() asm volatile("s_waitcnt lgkmcnt(0)\n\ts_barrier" ::: "memory")

extern "C" __device__ float __ocml_exp2_f32(float);
__device__ __forceinline__ float E2(float x) { return __ocml_exp2_f32(x); }
__device__ __forceinline__ float rcpf(float x) { return __builtin_amdgcn_rcpf(x); }

// Gates pre-scaled: zi,zf,zo = log2e*z ; zg = 2log2e*z ; cs = 2log2e*c.
// 5 exp + 2 rcp per element.
__device__ __forceinline__ _Float16 lstm_cell(float zi, float zf, float zg, float zo,
                                              float& cs) {
  float ei = E2(fminf(-zi, 40.0f));
  float ef = E2(fminf(-zf, 40.0f));
  float eg = E2(fminf(-zg, 40.0f));
  float eo = E2(fminf(-zo, 40.0f));
  float A = 1.0f + ei, B = 1.0f + eg, C = 1.0f + ef;
  float Q = A * B;
  float Pr = rcpf(Q * C);
  float fv = Pr * Q;                                  // sigmoid(zf)
  float Dp = __builtin_fmaf(eg, -TWO_L, TWO_L);       // 2log2e*(1-eg)
  cs = __builtin_fmaf(fv, cs, Dp * C * Pr);           // cs = f*cs + 2log2e*i*g
  float ec = E2(fminf(-cs, 40.0f));                   // e^{-2c}
  float Rr = rcpf((1.0f + eo) * (1.0f + ec));
  return (_Float16)((1.0f - ec) * Rr);                // sigmoid(zo)*tanh(c)
}

// ---------------------------------------------------------------------------
// Fused prep: xpad (A-frag fp16 x), scaled WhhT for both layers, scaled b1c.
// ---------------------------------------------------------------------------
__global__ void prep_all(const float* __restrict__ xa, const float* __restrict__ xp,
                         const float* __restrict__ xn,
                         const float* __restrict__ Whh1, const float* __restrict__ Whh2,
                         const float* __restrict__ bih1, const float* __restrict__ bhh1,
                         _Float16* __restrict__ xpad,
                         _Float16* __restrict__ whhT1, _Float16* __restrict__ whhT2,
                         float* __restrict__ b1c) {
  int bid = blockIdx.x, tid = threadIdx.x;
  if (bid < 6144) {                      // xpad: [96 tile][128 t][16 r][8 d]
    int i = bid * 256 + tid;
    int tile = i >> 14, rem = i & 16383;
    int t = rem >> 7, r = (rem >> 3) & 15, d = i & 7;
    int inp = tile >> 5, rloc = (tile & 31) * 16;
    const float* x = (inp == 0) ? xa : ((inp == 1) ? xp : xn);
    xpad[i] = (d < 5) ? (_Float16)x[(rloc + r) * 640 + t * 5 + d] : (_Float16)0.0f;
  } else if (bid < 6656) {               // whhT: [128 k][512 g], scaled
    int i = (bid - 6144) * 256 + tid;
    int which = i >> 16, idx = i & 65535;
    int k = idx >> 9, g = idx & 511;
    float sg = (g >= 256 && g < 384) ? TWO_L : ONE_L;
    const float* src = which ? Whh2 : Whh1;
    (which ? whhT2 : whhT1)[idx] = (_Float16)(src[g * HID + k] * sg);
  } else {                               // b1c, scaled
    int i = (bid - 6656) * 256 + tid;    // 512
    float sg = (i >= 256 && i < 384) ? TWO_L : ONE_L;
    b1c[i] = (bih1[i] + bhh1[i]) * sg;
  }
}

// ---------------------------------------------------------------------------
// LSTM layer 1. 96 WGs x 1024. hs1: [96 tile][128 t][2048 halves] A-frag order.
// ---------------------------------------------------------------------------
__global__ __launch_bounds__(1024, 1) void lstm1_kernel(
    const _Float16* __restrict__ xpad,   // [96][128][16][8]
    const float* __restrict__ Wih1,      // [512][5]
    const float* __restrict__ b1c,       // [512] scaled
    const _Float16* __restrict__ whhT,   // [128 k][512 g] scaled
    _Float16* __restrict__ hs1,
    float* __restrict__ s1sum, float* __restrict__ s1sq) {
  const int wg = blockIdx.x;             // tile 0..95
  const int inp = wg >> 5;
  const int tid = threadIdx.x;
  const int w = tid >> 6;                // 0..15
  const int hw = w & 7;                  // col group
  const int half = w >> 3;               // row half (0: rows quad*4+{0,1})
  const int lane = tid & 63;
  const int l15 = lane & 15;
  const int quad = lane >> 4;
  const int col = hw * 16 + l15;
  const int kb = quad * 8;

  __shared__ _Float16 hb[2][2048];       // double-buffered h, A-frag order, 8KB

  for (int i = tid; i < 4096; i += 1024) ((_Float16*)hb)[i] = (_Float16)0.0f;

  const int rbase = (quad * 16 + l15) * 8;
  // write index for row = quad*4 + half*2 + rr:
  const int wbase = (hw >> 1) * 512 + ((hw & 1) * 2 + (l15 >> 3)) * 128 +
                    (quad * 4 + half * 2) * 8 + (l15 & 7);

  half8 bh[4][4];                        // [kt][gate]
#pragma unroll
  for (int kt = 0; kt < 4; ++kt)
#pragma unroll
    for (int gt = 0; gt < 4; ++gt) {
      int gcol = gt * 128 + col;
      half8 v;
#pragma unroll
      for (int j = 0; j < 8; ++j) v[j] = whhT[(kt * 32 + kb + j) * NGATE + gcol];
      bh[kt][gt] = v;
    }
  half8 bx[4];                           // Wih1 K=32-padded, scaled (quad0, j<5)
#pragma unroll
  for (int gt = 0; gt < 4; ++gt) {
    half8 v = {0, 0, 0, 0, 0, 0, 0, 0};
    if (quad == 0) {
      float sg = (gt == 2) ? TWO_L : ONE_L;
#pragma unroll
      for (int j = 0; j < 5; ++j) v[j] = (_Float16)(Wih1[(gt * 128 + col) * 5 + j] * sg);
    }
    bx[gt] = v;
  }
  f32x4 biasv[4];
#pragma unroll
  for (int gt = 0; gt < 4; ++gt) {
    float b = b1c[gt * 128 + col];
    biasv[gt][0] = b; biasv[gt][1] = b; biasv[gt][2] = b; biasv[gt][3] = b;
  }

  half8 xp = {0, 0, 0, 0, 0, 0, 0, 0};
  if (quad == 0) xp = *(const half8*)&xpad[((size_t)(wg * TS) * 16 + l15) * 8];

  float cs[2] = {0, 0};
  float ssum = 0.0f, ssq = 0.0f;
  _Float16* hs1w = hs1 + (size_t)wg * TS * 2048;

  __syncthreads();                       // zero-init + B-frags staged

  for (int t = 0; t < TS; ++t) {
    f32x4 acc[4];
#pragma unroll
    for (int gt = 0; gt < 4; ++gt)
      acc[gt] = __builtin_amdgcn_mfma_f32_16x16x32_f16(xp, bx[gt], biasv[gt], 0, 0, 0);
    if (t + 1 < TS && quad == 0)
      xp = *(const half8*)&xpad[((size_t)(wg * TS + t + 1) * 16 + l15) * 8];
    BAR();                               // h(t-1) visible
    if (t > 0) {                         // coalesced h(t-1) -> global
      float cp = *(const float*)&hb[t & 1][tid * 2];
      *(float*)&hs1w[(size_t)(t - 1) * 2048 + tid * 2] = cp;
    }
#pragma unroll
    for (int kt = 0; kt < 4; ++kt) {
      half8 ah = *(const half8*)&hb[t & 1][kt * 512 + rbase];
#pragma unroll
      for (int gt = 0; gt < 4; ++gt)
        acc[gt] = __builtin_amdgcn_mfma_f32_16x16x32_f16(ah, bh[kt][gt], acc[gt], 0, 0, 0);
    }
    const int wb = (t + 1) & 1;
#pragma unroll
    for (int rr = 0; rr < 2; ++rr) {
      int r = half * 2 + rr;
      _Float16 hh = lstm_cell(acc[0][r], acc[1][r], acc[2][r], acc[3][r], cs[rr]);
      float hr = (float)hh;
      ssum += hr; ssq += hr * hr;
      hb[wb][wbase + rr * 8] = hh;
    }
  }
  BAR();                                 // h(127) visible
  {
    float cp = *(const float*)&hb[0][tid * 2];
    *(float*)&hs1w[(size_t)(TS - 1) * 2048 + tid * 2] = cp;
  }
  float s = ssum, q = ssq;
  s += __shfl_xor(s, 16); s += __shfl_xor(s, 32);
  q += __shfl_xor(q, 16); q += __shfl_xor(q, 32);
  if (quad == 0) {
    atomicAdd(&s1sum[inp * HID + col], s);
    atomicAdd(&s1sq[inp * HID + col], q);
  }
}

// ---------------------------------------------------------------------------
// Mid: BN1-folded scaled W2 (fp16) + effective bias2 (both log2e-scaled).
// ---------------------------------------------------------------------------
__global__ void mid_kernel(const float* __restrict__ s1sum, const float* __restrict__ s1sq,
                           const float* __restrict__ g1, const float* __restrict__ b1,
                           const float* __restrict__ Wih2,
                           const float* __restrict__ bih2, const float* __restrict__ bhh2,
                           _Float16* __restrict__ w2s, float* __restrict__ bias2eff) {
  int bid = blockIdx.x, tid = threadIdx.x;
  if (bid < 768) {                       // w2s: [3][128 k][512 g]
    int i = bid * 256 + tid;
    int inp = i >> 16, rem = i & 65535, k = rem >> 9, g = rem & 511;
    float m = s1sum[inp * HID + k] * INV_N;
    float v = s1sq[inp * HID + k] * INV_N - m * m;
    float sc = g1[k] * rsqrtf(v + 1e-5f);
    float sg = (g >= 256 && g < 384) ? TWO_L : ONE_L;
    w2s[i] = (_Float16)(sc * Wih2[g * HID + k] * sg);
  } else {                               // bias2eff: [3][512]
    int i = (bid - 768) * 256 + tid;
    int inp = i >> 9, g = i & 511;
    float acc = bih2[g] + bhh2[g];
    for (int h = 0; h < HID; ++h) {
      float m = s1sum[inp * HID + h] * INV_N;
      float v = s1sq[inp * HID + h] * INV_N - m * m;
      float sc = g1[h] * rsqrtf(v + 1e-5f);
      acc += (b1[h] - m * sc) * Wih2[g * HID + h];
    }
    float sg = (g >= 256 && g < 384) ? TWO_L : ONE_L;
    bias2eff[i] = acc * sg;
  }
}

// ---------------------------------------------------------------------------
// LSTM layer 2: fused (folded-BN1) input GEMM + recurrence. 96 WGs x 1024.
// ---------------------------------------------------------------------------
__global__ __launch_bounds__(1024, 1) void lstm2_kernel(
    const _Float16* __restrict__ hs1,    // [96][128][2048] A-frag order
    const _Float16* __restrict__ whhT2,  // [128 k][512 g] scaled
    const _Float16* __restrict__ w2s,    // [3][128 k][512 g] scaled
    const float* __restrict__ bias2eff,  // [3][512] scaled
    _Float16* __restrict__ h_last,       // [1536][128]
    float* __restrict__ s2sum, float* __restrict__ s2sq) {
  const int wg = blockIdx.x;             // tile 0..95
  const int inp = wg >> 5;
  const int gr0 = wg * 16;
  const int tid = threadIdx.x;
  const int w = tid >> 6;
  const int hw = w & 7;
  const int half = w >> 3;
  const int lane = tid & 63;
  const int l15 = lane & 15;
  const int quad = lane >> 4;
  const int col = hw * 16 + l15;
  const int kb = quad * 8;

  __shared__ _Float16 hb[2][2048];
  for (int i = tid; i < 4096; i += 1024) ((_Float16*)hb)[i] = (_Float16)0.0f;

  const int rbase = (quad * 16 + l15) * 8;
  const int wbase = (hw >> 1) * 512 + ((hw & 1) * 2 + (l15 >> 3)) * 128 +
                    (quad * 4 + half * 2) * 8 + (l15 & 7);

  const _Float16* w2sI = w2s + (size_t)inp * HID * NGATE;
  half8 bh[4][4], bxw[4][4];
#pragma unroll
  for (int kt = 0; kt < 4; ++kt)
#pragma unroll
    for (int gt = 0; gt < 4; ++gt) {
      int gcol = gt * 128 + col;
      half8 vh, vx;
#pragma unroll
      for (int j = 0; j < 8; ++j) {
        vh[j] = whhT2[(kt * 32 + kb + j) * NGATE + gcol];
        vx[j] = w2sI[(kt * 32 + kb + j) * NGATE + gcol];
      }
      bh[kt][gt] = vh;
      bxw[kt][gt] = vx;
    }
  f32x4 biasv[4];
#pragma unroll
  for (int gt = 0; gt < 4; ++gt) {
    float b = bias2eff[inp * NGATE + gt * 128 + col];
    biasv[gt][0] = b; biasv[gt][1] = b; biasv[gt][2] = b; biasv[gt][3] = b;
  }

  const _Float16* hg = hs1 + (size_t)wg * TS * 2048;
  half8 xp[4];
#pragma unroll
  for (int kt = 0; kt < 4; ++kt)
    xp[kt] = *(const half8*)&hg[kt * 512 + rbase];

  float cs[2] = {0, 0};
  float ssum = 0.0f, ssq = 0.0f;

  __syncthreads();

  for (int t = 0; t < TS; ++t) {
    f32x4 acc[4];
#pragma unroll
    for (int gt = 0; gt < 4; ++gt)
      acc[gt] = __builtin_amdgcn_mfma_f32_16x16x32_f16(xp[0], bxw[0][gt], biasv[gt], 0, 0, 0);
#pragma unroll
    for (int kt = 1; kt < 4; ++kt)
#pragma unroll
      for (int gt = 0; gt < 4; ++gt)
        acc[gt] = __builtin_amdgcn_mfma_f32_16x16x32_f16(xp[kt], bxw[kt][gt], acc[gt], 0, 0, 0);
    if (t + 1 < TS) {
#pragma unroll
      for (int kt = 0; kt < 4; ++kt)
        xp[kt] = *(const half8*)&hg[(size_t)(t + 1) * 2048 + kt * 512 + rbase];
    }
    BAR();
#pragma unroll
    for (int kt = 0; kt < 4; ++kt) {
      half8 ah = *(const half8*)&hb[t & 1][kt * 512 + rbase];
#pragma unroll
      for (int gt = 0; gt < 4; ++gt)
        acc[gt] = __builtin_amdgcn_mfma_f32_16x16x32_f16(ah, bh[kt][gt], acc[gt], 0, 0, 0);
    }
    const int wb = (t + 1) & 1;
#pragma unroll
    for (int rr = 0; rr < 2; ++rr) {
      int r = half * 2 + rr;
      _Float16 hh = lstm_cell(acc[0][r], acc[1][r], acc[2][r], acc[3][r], cs[rr]);
      float hr = (float)hh;
      ssum += hr; ssq += hr * hr;
      hb[wb][wbase + rr * 8] = hh;
      if (t == TS - 1) h_last[(size_t)(gr0 + quad * 4 + r) * HID + col] = hh;
    }
  }

  float s = ssum, q = ssq;
  s += __shfl_xor(s, 16); s += __shfl_xor(s, 32);
  q += __shfl_xor(q, 16); q += __shfl_xor(q, 32);
  if (quad == 0) {
    atomicAdd(&s2sum[inp * HID + col], s);
    atomicAdd(&s2sq[inp * HID + col], q);
  }
}

// ---------------------------------------------------------------------------
// Head: BN2 finalize + FC + L2 normalize. 96 WGs x 16 rows.
// ---------------------------------------------------------------------------
__global__ __launch_bounds__(256, 1) void head_kernel(
    const _Float16* __restrict__ h_last,
    const float* __restrict__ s2sum, const float* __restrict__ s2sq,
    const float* __restrict__ g2, const float* __restrict__ b2,
    const float* __restrict__ fcW, const float* __restrict__ fcb,
    float* __restrict__ out) {
  const int wg = blockIdx.x;
  const int inp = wg >> 5;
  const int gr0 = wg * 16;
  const int tid = threadIdx.x;

  __shared__ float fcwT[128][132];       // fcwT[h][j] = fcW[j][h]
  __shared__ float bnh[16][132];
  __shared__ float s2[128], sh2[128];
  __shared__ float part[16][16];
  __shared__ float inv[16];

  if (tid < 128) {
    float m = s2sum[inp * HID + tid] * INV_N;
    float v = s2sq[inp * HID + tid] * INV_N - m * m;
    float s = g2[tid] * rsqrtf(v + 1e-5f);
    s2[tid] = s; sh2[tid] = b2[tid] - m * s;
  }
  for (int i = tid; i < 16384; i += 256) {
    int j = i >> 7, h = i & 127;
    fcwT[h][j] = fcW[i];
  }
  __syncthreads();
  {
    int row = tid >> 4, c0 = (tid & 15) * 8;
#pragma unroll
    for (int k = 0; k < 8; ++k) {
      int h = c0 + k;
      bnh[row][h] = (float)h_last[(gr0 + row) * HID + h] * s2[h] + sh2[h];
    }
  }
  __syncthreads();
  const int row = tid >> 4, jl = tid & 15;
  float emb[8];
  float sq = 0.0f;
#pragma unroll
  for (int jj = 0; jj < 8; ++jj) {
    int j = jl + jj * 16;
    float acc = fcb[j];
    for (int h = 0; h < HID; ++h) acc += bnh[row][h] * fcwT[h][j];
    emb[jj] = acc; sq += acc * acc;
  }
  part[row][jl] = sq;
  __syncthreads();
  if (tid < 16) {
    float s = 0.0f;
    for (int k = 0; k < 16; ++k) s += part[tid][k];
    float nrm = sqrtf(s);
    inv[tid] = 1.0f / fmaxf(nrm, 1e-12f);
  }
  __syncthreads();
#pragma unroll
  for (int jj = 0; jj < 8; ++jj)
    out[(gr0 + row) * HID + jl + jj * 16] = emb[jj] * inv[row];
}

// ---------------------------------------------------------------------------
extern "C" void kernel_launch(void* const* d_in, const int* in_sizes, int n_in,
                              void* d_out, int out_size, void* d_ws, size_t ws_size,
                              hipStream_t stream) {
  const float* a    = (const float*)d_in[0];
  const float* p    = (const float*)d_in[1];
  const float* nn   = (const float*)d_in[2];
  const float* Wih1 = (const float*)d_in[3];
  const float* Whh1 = (const float*)d_in[4];
  const float* bih1 = (const float*)d_in[5];
  const float* bhh1 = (const float*)d_in[6];
  const float* g1   = (const float*)d_in[7];
  const float* b1   = (const float*)d_in[8];
  const float* Wih2 = (const float*)d_in[9];
  const float* Whh2 = (const float*)d_in[10];
  const float* bih2 = (const float*)d_in[11];
  const float* bhh2 = (const float*)d_in[12];
  const float* g2   = (const float*)d_in[13];
  const float* b2   = (const float*)d_in[14];
  const float* fcW  = (const float*)d_in[15];
  const float* fcb  = (const float*)d_in[16];

  char* ws = (char*)d_ws;
  float* s1sum = (float*)(ws + 0);            // 384 f32
  float* s1sq  = s1sum + 384;
  float* s2sum = s1sum + 768;
  float* s2sq  = s1sum + 1152;                // stats end @6144B
  float* b1c      = (float*)(ws + 6144);      // 512 f32 -> @8192
  float* bias2eff = (float*)(ws + 8192);      // 1536 f32 -> @14336
  _Float16* whhT1 = (_Float16*)(ws + 14336);    // 131072B -> @145408
  _Float16* whhT2 = (_Float16*)(ws + 145408);   // 131072B -> @276480
  _Float16* w2s   = (_Float16*)(ws + 276480);   // 393216B -> @669696
  _Float16* hlast = (_Float16*)(ws + 669696);   // 393216B -> @1062912
  _Float16* xpad  = (_Float16*)(ws + 1062912);  // 3145728B -> @4208640
  _Float16* hs1   = (_Float16*)(ws + 4208640);  // 50331648B -> ~54.5MB total

  hipMemsetAsync(ws, 0, 6144, stream);  // zero BN stats accumulators

  prep_all<<<6658, 256, 0, stream>>>(a, p, nn, Whh1, Whh2, bih1, bhh1,
                                     xpad, whhT1, whhT2, b1c);
  lstm1_kernel<<<96, 1024, 0, stream>>>(xpad, Wih1, b1c, whhT1, hs1, s1sum, s1sq);
  mid_kernel<<<774, 256, 0, stream>>>(s1sum, s1sq, g1, b1, Wih2, bih2, bhh2,
                                      w2s, bias2eff);
  lstm2_kernel<<<96, 1024, 0, stream>>>(hs1, whhT2, w2s, bias2eff, hlast, s2sum, s2sq);
  head_kernel<<<96, 256, 0, stream>>>(hlast, s2sum, s2sq, g2, b2, fcW, fcb, (float*)d_out);
}

// Round 6
// 462.865 us; speedup vs baseline: 3.4674x; 3.4674x over previous
//
#include <hip/hip_runtime.h>

// ============================================================================
// TypeNet triplet embedder: 2x(LSTM + BatchNorm) + FC + L2norm, for a,p,n.
// Round 6: producer/consumer wave specialization, 96 WGs x 1024 thr.
//  - Waves 0-7 (consumers): own h-cols [16w,16w+16); per step: read xw ring
//    (f32 C-layout) + bias, 16 h-MFMAs, lstm_cell, write h to LDS A-frag buf.
//  - Waves 8-15 (producers): compute xw[t+1] = x(t+1)@W^T one step ahead into
//    a 2-slot LDS ring; lstm1 producers also copy h(t-1) LDS->hs1 (coalesced).
//  - amdgpu_waves_per_eu(4,4): pins VGPR budget to 128/wave (R5 failed because
//    launch_bounds(1024,1) let the compiler pick 64 VGPRs -> massive spills).
//  - BAR = s_waitcnt lgkmcnt(0) + s_barrier (no vmcnt drain); one BAR/step.
//  - log2e-prescaled weights: 5 exp2 + 2 rcp per element, cs = 2log2e*c.
// ============================================================================

typedef __attribute__((ext_vector_type(8))) _Float16 half8;
typedef __attribute__((ext_vector_type(4))) float f32x4;

#define TS 128
#define HID 128
#define NGATE 512
#define INV_N (1.0f/65536.0f)   // 1/(B*T)
#define ONE_L 1.4426950408889634f
#define TWO_L 2.8853900817779268f

#define BAR() asm volatile("s_waitcnt lgkmcnt(0)\n\ts_barrier" ::: "memory")

extern "C" __device__ float __ocml_exp2_f32(float);
__device__ __forceinline__ float E2(float x) { return __ocml_exp2_f32(x); }
__device__ __forceinline__ float rcpf(float x) { return __builtin_amdgcn_rcpf(x); }

// Gates pre-scaled: zi,zf,zo = log2e*z ; zg = 2log2e*z ; cs = 2log2e*c.
__device__ __forceinline__ _Float16 lstm_cell(float zi, float zf, float zg, float zo,
                                              float& cs) {
  float ei = E2(fminf(-zi, 40.0f));
  float ef = E2(fminf(-zf, 40.0f));
  float eg = E2(fminf(-zg, 40.0f));
  float eo = E2(fminf(-zo, 40.0f));
  float A = 1.0f + ei, B = 1.0f + eg, C = 1.0f + ef;
  float Q = A * B;
  float Pr = rcpf(Q * C);
  float fv = Pr * Q;                                  // sigmoid(zf)
  float Dp = __builtin_fmaf(eg, -TWO_L, TWO_L);       // 2log2e*(1-eg)
  cs = __builtin_fmaf(fv, cs, Dp * C * Pr);           // cs = f*cs + 2log2e*i*g
  float ec = E2(fminf(-cs, 40.0f));
  float Rr = rcpf((1.0f + eo) * (1.0f + ec));
  return (_Float16)((1.0f - ec) * Rr);                // sigmoid(zo)*tanh(c)
}

// ---------------------------------------------------------------------------
// Fused prep: xpad (A-frag fp16 x), scaled WhhT for both layers, scaled b1c.
// ---------------------------------------------------------------------------
__global__ void prep_all(const float* __restrict__ xa, const float* __restrict__ xp,
                         const float* __restrict__ xn,
                         const float* __restrict__ Whh1, const float* __restrict__ Whh2,
                         const float* __restrict__ bih1, const float* __restrict__ bhh1,
                         _Float16* __restrict__ xpad,
                         _Float16* __restrict__ whhT1, _Float16* __restrict__ whhT2,
                         float* __restrict__ b1c) {
  int bid = blockIdx.x, tid = threadIdx.x;
  if (bid < 6144) {                      // xpad: [96 tile][128 t][16 r][8 d]
    int i = bid * 256 + tid;
    int tile = i >> 14, rem = i & 16383;
    int t = rem >> 7, r = (rem >> 3) & 15, d = i & 7;
    int inp = tile >> 5, rloc = (tile & 31) * 16;
    const float* x = (inp == 0) ? xa : ((inp == 1) ? xp : xn);
    xpad[i] = (d < 5) ? (_Float16)x[(rloc + r) * 640 + t * 5 + d] : (_Float16)0.0f;
  } else if (bid < 6656) {               // whhT: [128 k][512 g], scaled
    int i = (bid - 6144) * 256 + tid;
    int which = i >> 16, idx = i & 65535;
    int k = idx >> 9, g = idx & 511;
    float sg = (g >= 256 && g < 384) ? TWO_L : ONE_L;
    const float* src = which ? Whh2 : Whh1;
    (which ? whhT2 : whhT1)[idx] = (_Float16)(src[g * HID + k] * sg);
  } else {                               // b1c, scaled
    int i = (bid - 6656) * 256 + tid;    // 512
    float sg = (i >= 256 && i < 384) ? TWO_L : ONE_L;
    b1c[i] = (bih1[i] + bhh1[i]) * sg;
  }
}

// ---------------------------------------------------------------------------
// LSTM layer 1. 96 WGs x 1024. hs1: [96 tile][128 t][2048 halves] A-frag order.
// ---------------------------------------------------------------------------
__global__ __attribute__((amdgpu_waves_per_eu(4, 4))) __launch_bounds__(1024)
void lstm1_kernel(
    const _Float16* __restrict__ xpad,   // [96][128][16][8]
    const float* __restrict__ Wih1,      // [512][5]
    const float* __restrict__ b1c,       // [512] scaled
    const _Float16* __restrict__ whhT,   // [128 k][512 g] scaled
    _Float16* __restrict__ hs1,
    float* __restrict__ s1sum, float* __restrict__ s1sq) {
  const int wg = blockIdx.x;             // tile 0..95
  const int inp = wg >> 5;
  const int tid = threadIdx.x;
  const int w = tid >> 6;                // 0..15
  const int lane = tid & 63;
  const int l15 = lane & 15;
  const int quad = lane >> 4;
  const int hw = w & 7;
  const int col = hw * 16 + l15;
  const int kb = quad * 8;

  __shared__ _Float16 hb[2][2048];       // double-buffered h, A-frag order, 8 KB
  __shared__ float xwr[2][8][4][256];    // xW ring: [slot][wave][gate][lane*4], 64 KB
  for (int i = tid; i < 4096; i += 1024) ((_Float16*)hb)[i] = (_Float16)0.0f;
  __syncthreads();

  _Float16* hs1w = hs1 + (size_t)wg * TS * 2048;

  if (w < 8) {
    // ======================= consumers =======================
    half8 bh[4][4];                      // [kt][gate]
#pragma unroll
    for (int kt = 0; kt < 4; ++kt)
#pragma unroll
      for (int gt = 0; gt < 4; ++gt) {
        int gcol = gt * 128 + col;
        half8 v;
#pragma unroll
        for (int j = 0; j < 8; ++j) v[j] = whhT[(kt * 32 + kb + j) * NGATE + gcol];
        bh[kt][gt] = v;
      }
    f32x4 biasv[4];
#pragma unroll
    for (int gt = 0; gt < 4; ++gt) {
      float b = b1c[gt * 128 + col];
      biasv[gt][0] = b; biasv[gt][1] = b; biasv[gt][2] = b; biasv[gt][3] = b;
    }
    const int rbase = (quad * 16 + l15) * 8;
    const int wbase = (hw >> 1) * 512 + ((hw & 1) * 2 + (l15 >> 3)) * 128 +
                      quad * 32 + (l15 & 7);
    float cs[4] = {0, 0, 0, 0};
    float ssum = 0.0f, ssq = 0.0f;

    for (int t = 0; t < TS; ++t) {
      BAR();                             // xw[t] (slot t&1) + h(t-1) visible
      f32x4 acc[4];
#pragma unroll
      for (int gt = 0; gt < 4; ++gt) {
        acc[gt] = *(const f32x4*)&xwr[t & 1][hw][gt][lane << 2];
        acc[gt] += biasv[gt];
      }
#pragma unroll
      for (int kt = 0; kt < 4; ++kt) {
        half8 ah = *(const half8*)&hb[t & 1][kt * 512 + rbase];
#pragma unroll
        for (int gt = 0; gt < 4; ++gt)
          acc[gt] = __builtin_amdgcn_mfma_f32_16x16x32_f16(ah, bh[kt][gt], acc[gt], 0, 0, 0);
      }
      const int wb = (t + 1) & 1;
#pragma unroll
      for (int r = 0; r < 4; ++r) {
        _Float16 hh = lstm_cell(acc[0][r], acc[1][r], acc[2][r], acc[3][r], cs[r]);
        float hr = (float)hh;
        ssum += hr; ssq += hr * hr;
        hb[wb][wbase + r * 8] = hh;
      }
    }
    BAR();                               // h(127) visible (producers copy it)
    float s = ssum, q = ssq;
    s += __shfl_xor(s, 16); s += __shfl_xor(s, 32);
    q += __shfl_xor(q, 16); q += __shfl_xor(q, 32);
    if (quad == 0) {
      atomicAdd(&s1sum[inp * HID + col], s);
      atomicAdd(&s1sq[inp * HID + col], q);
    }
  } else {
    // ======================= producers =======================
    half8 bx[4];                         // Wih1 K=32-padded, scaled (quad0, j<5)
#pragma unroll
    for (int gt = 0; gt < 4; ++gt) {
      half8 v = {0, 0, 0, 0, 0, 0, 0, 0};
      if (quad == 0) {
        float sg = (gt == 2) ? TWO_L : ONE_L;
#pragma unroll
        for (int j = 0; j < 5; ++j) v[j] = (_Float16)(Wih1[(gt * 128 + col) * 5 + j] * sg);
      }
      bx[gt] = v;
    }
    const int ptid = tid - 512;          // 0..511
    const f32x4 zero4 = {0, 0, 0, 0};
    half8 xp = {0, 0, 0, 0, 0, 0, 0, 0};
    if (quad == 0) xp = *(const half8*)&xpad[((size_t)(wg * TS) * 16 + l15) * 8];
    {                                    // produce slot 0 (xw[0], no bias)
      f32x4 acc[4];
#pragma unroll
      for (int gt = 0; gt < 4; ++gt)
        acc[gt] = __builtin_amdgcn_mfma_f32_16x16x32_f16(xp, bx[gt], zero4, 0, 0, 0);
#pragma unroll
      for (int gt = 0; gt < 4; ++gt)
        *(f32x4*)&xwr[0][hw][gt][lane << 2] = acc[gt];
    }
    if (quad == 0) xp = *(const half8*)&xpad[((size_t)(wg * TS + 1) * 16 + l15) * 8];

    for (int t = 0; t < TS; ++t) {
      BAR();
      if (t > 0)                         // copy h(t-1) -> hs1 (coalesced 16B/thr)
        *(f32x4*)&hs1w[(size_t)(t - 1) * 2048 + ptid * 8] =
            *(const f32x4*)&hb[t & 1][ptid * 8];
      if (t + 1 < TS) {                  // produce xw[t+1] into slot (t+1)&1
        f32x4 acc[4];
#pragma unroll
        for (int gt = 0; gt < 4; ++gt)
          acc[gt] = __builtin_amdgcn_mfma_f32_16x16x32_f16(xp, bx[gt], zero4, 0, 0, 0);
#pragma unroll
        for (int gt = 0; gt < 4; ++gt)
          *(f32x4*)&xwr[(t + 1) & 1][hw][gt][lane << 2] = acc[gt];
        if (t + 2 < TS && quad == 0)
          xp = *(const half8*)&xpad[((size_t)(wg * TS + t + 2) * 16 + l15) * 8];
      }
    }
    BAR();                               // h(127) visible
    *(f32x4*)&hs1w[(size_t)(TS - 1) * 2048 + ptid * 8] =
        *(const f32x4*)&hb[0][ptid * 8];
  }
}

// ---------------------------------------------------------------------------
// Mid: BN1-folded scaled W2 (fp16) + effective bias2 (both log2e-scaled).
// ---------------------------------------------------------------------------
__global__ void mid_kernel(const float* __restrict__ s1sum, const float* __restrict__ s1sq,
                           const float* __restrict__ g1, const float* __restrict__ b1,
                           const float* __restrict__ Wih2,
                           const float* __restrict__ bih2, const float* __restrict__ bhh2,
                           _Float16* __restrict__ w2s, float* __restrict__ bias2eff) {
  int bid = blockIdx.x, tid = threadIdx.x;
  if (bid < 768) {                       // w2s: [3][128 k][512 g]
    int i = bid * 256 + tid;
    int inp = i >> 16, rem = i & 65535, k = rem >> 9, g = rem & 511;
    float m = s1sum[inp * HID + k] * INV_N;
    float v = s1sq[inp * HID + k] * INV_N - m * m;
    float sc = g1[k] * rsqrtf(v + 1e-5f);
    float sg = (g >= 256 && g < 384) ? TWO_L : ONE_L;
    w2s[i] = (_Float16)(sc * Wih2[g * HID + k] * sg);
  } else {                               // bias2eff: [3][512]
    int i = (bid - 768) * 256 + tid;
    int inp = i >> 9, g = i & 511;
    float acc = bih2[g] + bhh2[g];
    for (int h = 0; h < HID; ++h) {
      float m = s1sum[inp * HID + h] * INV_N;
      float v = s1sq[inp * HID + h] * INV_N - m * m;
      float sc = g1[h] * rsqrtf(v + 1e-5f);
      acc += (b1[h] - m * sc) * Wih2[g * HID + h];
    }
    float sg = (g >= 256 && g < 384) ? TWO_L : ONE_L;
    bias2eff[i] = acc * sg;
  }
}

// ---------------------------------------------------------------------------
// LSTM layer 2: producers do the folded-BN1 input GEMM one step ahead.
// ---------------------------------------------------------------------------
__global__ __attribute__((amdgpu_waves_per_eu(4, 4))) __launch_bounds__(1024)
void lstm2_kernel(
    const _Float16* __restrict__ hs1,    // [96][128][2048] A-frag order
    const _Float16* __restrict__ whhT2,  // [128 k][512 g] scaled
    const _Float16* __restrict__ w2s,    // [3][128 k][512 g] scaled
    const float* __restrict__ bias2eff,  // [3][512] scaled
    _Float16* __restrict__ h_last,       // [1536][128]
    float* __restrict__ s2sum, float* __restrict__ s2sq) {
  const int wg = blockIdx.x;             // tile 0..95
  const int inp = wg >> 5;
  const int gr0 = wg * 16;
  const int tid = threadIdx.x;
  const int w = tid >> 6;
  const int lane = tid & 63;
  const int l15 = lane & 15;
  const int quad = lane >> 4;
  const int hw = w & 7;
  const int col = hw * 16 + l15;
  const int kb = quad * 8;

  __shared__ _Float16 hb[2][2048];
  __shared__ float xwr[2][8][4][256];
  for (int i = tid; i < 4096; i += 1024) ((_Float16*)hb)[i] = (_Float16)0.0f;
  __syncthreads();

  const int rbase = (quad * 16 + l15) * 8;

  if (w < 8) {
    // ======================= consumers =======================
    half8 bh[4][4];
#pragma unroll
    for (int kt = 0; kt < 4; ++kt)
#pragma unroll
      for (int gt = 0; gt < 4; ++gt) {
        int gcol = gt * 128 + col;
        half8 v;
#pragma unroll
        for (int j = 0; j < 8; ++j) v[j] = whhT2[(kt * 32 + kb + j) * NGATE + gcol];
        bh[kt][gt] = v;
      }
    f32x4 biasv[4];
#pragma unroll
    for (int gt = 0; gt < 4; ++gt) {
      float b = bias2eff[inp * NGATE + gt * 128 + col];
      biasv[gt][0] = b; biasv[gt][1] = b; biasv[gt][2] = b; biasv[gt][3] = b;
    }
    const int wbase = (hw >> 1) * 512 + ((hw & 1) * 2 + (l15 >> 3)) * 128 +
                      quad * 32 + (l15 & 7);
    float cs[4] = {0, 0, 0, 0};
    float ssum = 0.0f, ssq = 0.0f;

    for (int t = 0; t < TS; ++t) {
      BAR();
      f32x4 acc[4];
#pragma unroll
      for (int gt = 0; gt < 4; ++gt) {
        acc[gt] = *(const f32x4*)&xwr[t & 1][hw][gt][lane << 2];
        acc[gt] += biasv[gt];
      }
#pragma unroll
      for (int kt = 0; kt < 4; ++kt) {
        half8 ah = *(const half8*)&hb[t & 1][kt * 512 + rbase];
#pragma unroll
        for (int gt = 0; gt < 4; ++gt)
          acc[gt] = __builtin_amdgcn_mfma_f32_16x16x32_f16(ah, bh[kt][gt], acc[gt], 0, 0, 0);
      }
      const int wb = (t + 1) & 1;
#pragma unroll
      for (int r = 0; r < 4; ++r) {
        _Float16 hh = lstm_cell(acc[0][r], acc[1][r], acc[2][r], acc[3][r], cs[r]);
        float hr = (float)hh;
        ssum += hr; ssq += hr * hr;
        hb[wb][wbase + r * 8] = hh;
        if (t == TS - 1) h_last[(size_t)(gr0 + quad * 4 + r) * HID + col] = hh;
      }
    }
    float s = ssum, q = ssq;
    s += __shfl_xor(s, 16); s += __shfl_xor(s, 32);
    q += __shfl_xor(q, 16); q += __shfl_xor(q, 32);
    if (quad == 0) {
      atomicAdd(&s2sum[inp * HID + col], s);
      atomicAdd(&s2sq[inp * HID + col], q);
    }
  } else {
    // ======================= producers =======================
    const _Float16* w2sI = w2s + (size_t)inp * HID * NGATE;
    half8 bxw[4][4];
#pragma unroll
    for (int kt = 0; kt < 4; ++kt)
#pragma unroll
      for (int gt = 0; gt < 4; ++gt) {
        int gcol = gt * 128 + col;
        half8 v;
#pragma unroll
        for (int j = 0; j < 8; ++j) v[j] = w2sI[(kt * 32 + kb + j) * NGATE + gcol];
        bxw[kt][gt] = v;
      }
    const _Float16* hg = hs1 + (size_t)wg * TS * 2048;
    const f32x4 zero4 = {0, 0, 0, 0};
    half8 xp[4];
#pragma unroll
    for (int kt = 0; kt < 4; ++kt)
      xp[kt] = *(const half8*)&hg[kt * 512 + rbase];
    {                                    // produce slot 0 (xw[0], no bias)
      f32x4 acc[4];
#pragma unroll
      for (int gt = 0; gt < 4; ++gt)
        acc[gt] = __builtin_amdgcn_mfma_f32_16x16x32_f16(xp[0], bxw[0][gt], zero4, 0, 0, 0);
#pragma unroll
      for (int kt = 1; kt < 4; ++kt)
#pragma unroll
        for (int gt = 0; gt < 4; ++gt)
          acc[gt] = __builtin_amdgcn_mfma_f32_16x16x32_f16(xp[kt], bxw[kt][gt], acc[gt], 0, 0, 0);
#pragma unroll
      for (int gt = 0; gt < 4; ++gt)
        *(f32x4*)&xwr[0][hw][gt][lane << 2] = acc[gt];
    }
#pragma unroll
    for (int kt = 0; kt < 4; ++kt)       // prefetch t=1
      xp[kt] = *(const half8*)&hg[(size_t)2048 + kt * 512 + rbase];

    for (int t = 0; t < TS; ++t) {
      BAR();
      if (t + 1 < TS) {                  // produce xw[t+1] into slot (t+1)&1
        f32x4 acc[4];
#pragma unroll
        for (int gt = 0; gt < 4; ++gt)
          acc[gt] = __builtin_amdgcn_mfma_f32_16x16x32_f16(xp[0], bxw[0][gt], zero4, 0, 0, 0);
#pragma unroll
        for (int kt = 1; kt < 4; ++kt)
#pragma unroll
          for (int gt = 0; gt < 4; ++gt)
            acc[gt] = __builtin_amdgcn_mfma_f32_16x16x32_f16(xp[kt], bxw[kt][gt], acc[gt], 0, 0, 0);
#pragma unroll
        for (int gt = 0; gt < 4; ++gt)
          *(f32x4*)&xwr[(t + 1) & 1][hw][gt][lane << 2] = acc[gt];
        if (t + 2 < TS) {
#pragma unroll
          for (int kt = 0; kt < 4; ++kt)
            xp[kt] = *(const half8*)&hg[(size_t)(t + 2) * 2048 + kt * 512 + rbase];
        }
      }
    }
  }
}

// ---------------------------------------------------------------------------
// Head: BN2 finalize + FC + L2 normalize. 96 WGs x 16 rows.
// ---------------------------------------------------------------------------
__global__ __launch_bounds__(256, 1) void head_kernel(
    const _Float16* __restrict__ h_last,
    const float* __restrict__ s2sum, const float* __restrict__ s2sq,
    const float* __restrict__ g2, const float* __restrict__ b2,
    const float* __restrict__ fcW, const float* __restrict__ fcb,
    float* __restrict__ out) {
  const int wg = blockIdx.x;
  const int inp = wg >> 5;
  const int gr0 = wg * 16;
  const int tid = threadIdx.x;

  __shared__ float fcwT[128][132];       // fcwT[h][j] = fcW[j][h]
  __shared__ float bnh[16][132];
  __shared__ float s2[128], sh2[128];
  __shared__ float part[16][16];
  __shared__ float inv[16];

  if (tid < 128) {
    float m = s2sum[inp * HID + tid] * INV_N;
    float v = s2sq[inp * HID + tid] * INV_N - m * m;
    float s = g2[tid] * rsqrtf(v + 1e-5f);
    s2[tid] = s; sh2[tid] = b2[tid] - m * s;
  }
  for (int i = tid; i < 16384; i += 256) {
    int j = i >> 7, h = i & 127;
    fcwT[h][j] = fcW[i];
  }
  __syncthreads();
  {
    int row = tid >> 4, c0 = (tid & 15) * 8;
#pragma unroll
    for (int k = 0; k < 8; ++k) {
      int h = c0 + k;
      bnh[row][h] = (float)h_last[(gr0 + row) * HID + h] * s2[h] + sh2[h];
    }
  }
  __syncthreads();
  const int row = tid >> 4, jl = tid & 15;
  float emb[8];
  float sq = 0.0f;
#pragma unroll
  for (int jj = 0; jj < 8; ++jj) {
    int j = jl + jj * 16;
    float acc = fcb[j];
    for (int h = 0; h < HID; ++h) acc += bnh[row][h] * fcwT[h][j];
    emb[jj] = acc; sq += acc * acc;
  }
  part[row][jl] = sq;
  __syncthreads();
  if (tid < 16) {
    float s = 0.0f;
    for (int k = 0; k < 16; ++k) s += part[tid][k];
    float nrm = sqrtf(s);
    inv[tid] = 1.0f / fmaxf(nrm, 1e-12f);
  }
  __syncthreads();
#pragma unroll
  for (int jj = 0; jj < 8; ++jj)
    out[(gr0 + row) * HID + jl + jj * 16] = emb[jj] * inv[row];
}

// ---------------------------------------------------------------------------
extern "C" void kernel_launch(void* const* d_in, const int* in_sizes, int n_in,
                              void* d_out, int out_size, void* d_ws, size_t ws_size,
                              hipStream_t stream) {
  const float* a    = (const float*)d_in[0];
  const float* p    = (const float*)d_in[1];
  const float* nn   = (const float*)d_in[2];
  const float* Wih1 = (const float*)d_in[3];
  const float* Whh1 = (const float*)d_in[4];
  const float* bih1 = (const float*)d_in[5];
  const float* bhh1 = (const float*)d_in[6];
  const float* g1   = (const float*)d_in[7];
  const float* b1   = (const float*)d_in[8];
  const float* Wih2 = (const float*)d_in[9];
  const float* Whh2 = (const float*)d_in[10];
  const float* bih2 = (const float*)d_in[11];
  const float* bhh2 = (const float*)d_in[12];
  const float* g2   = (const float*)d_in[13];
  const float* b2   = (const float*)d_in[14];
  const float* fcW  = (const float*)d_in[15];
  const float* fcb  = (const float*)d_in[16];

  char* ws = (char*)d_ws;
  float* s1sum = (float*)(ws + 0);            // 384 f32
  float* s1sq  = s1sum + 384;
  float* s2sum = s1sum + 768;
  float* s2sq  = s1sum + 1152;                // stats end @6144B
  float* b1c      = (float*)(ws + 6144);      // 512 f32 -> @8192
  float* bias2eff = (float*)(ws + 8192);      // 1536 f32 -> @14336
  _Float16* whhT1 = (_Float16*)(ws + 14336);    // 131072B -> @145408
  _Float16* whhT2 = (_Float16*)(ws + 145408);   // 131072B -> @276480
  _Float16* w2s   = (_Float16*)(ws + 276480);   // 393216B -> @669696
  _Float16* hlast = (_Float16*)(ws + 669696);   // 393216B -> @1062912
  _Float16* xpad  = (_Float16*)(ws + 1062912);  // 3145728B -> @4208640
  _Float16* hs1   = (_Float16*)(ws + 4208640);  // 50331648B -> ~54.5MB total

  hipMemsetAsync(ws, 0, 6144, stream);  // zero BN stats accumulators

  prep_all<<<6658, 256, 0, stream>>>(a, p, nn, Whh1, Whh2, bih1, bhh1,
                                     xpad, whhT1, whhT2, b1c);
  lstm1_kernel<<<96, 1024, 0, stream>>>(xpad, Wih1, b1c, whhT1, hs1, s1sum, s1sq);
  mid_kernel<<<774, 256, 0, stream>>>(s1sum, s1sq, g1, b1, Wih2, bih2, bhh2,
                                      w2s, bias2eff);
  lstm2_kernel<<<96, 1024, 0, stream>>>(hs1, whhT2, w2s, bias2eff, hlast, s2sum, s2sq);
  head_kernel<<<96, 256, 0, stream>>>(hlast, s2sum, s2sq, g2, b2, fcW, fcb, (float*)d_out);
}

// Round 7
// 369.233 us; speedup vs baseline: 4.3467x; 1.2536x over previous
//
#include <hip/hip_runtime.h>

// ============================================================================
// TypeNet triplet embedder: 2x(LSTM + BatchNorm) + FC + L2norm, for a,p,n.
// Round 7: consolidate proven wins on the R3 base.
//  - 96 WGs x 512 thr, monolithic waves (VGPR 124, no spills — R3-proven).
//  - Conflict-free A-frag LDS h layout (R4/R6-proven mapping).
//  - hs1 stored in A-frag order: lstm1 writes via cooperative coalesced
//    float2 copy; lstm2 prefetch reads are lane-contiguous 16B.
//  - 2-deep register prefetch of hs1 tiles in lstm2 (survives BAR).
//  - BAR = s_waitcnt lgkmcnt(0) + s_barrier (no vmcnt drain).
//  - R3's proven lstm_cell (absmax 1.95e-3).
// ============================================================================

typedef __attribute__((ext_vector_type(8))) _Float16 half8;
typedef __attribute__((ext_vector_type(4))) float f32x4;

#define TS 128
#define HID 128
#define NGATE 512
#define INV_N (1.0f/65536.0f)   // 1/(B*T)

#define BAR() asm volatile("s_waitcnt lgkmcnt(0)\n\ts_barrier" ::: "memory")

__device__ __forceinline__ float rcpf(float x) { return __builtin_amdgcn_rcpf(x); }
__device__ __forceinline__ float clamp20(float x) { return fminf(fmaxf(x, -20.0f), 20.0f); }

// Fused LSTM gate elementwise (R3-proven): 5 exp + 3 rcp per element.
__device__ __forceinline__ _Float16 lstm_cell(float zi, float zf, float zg, float zo,
                                              float& c) {
  zg = clamp20(zg);
  float ei = __expf(-zi);
  float eg = __expf(-2.0f * zg);
  float ef = __expf(-zf);
  float fv = rcpf(1.0f + ef);
  float ig = (1.0f - eg) * rcpf((1.0f + ei) * (1.0f + eg));  // sigmoid(zi)*tanh(zg)
  float cc = fv * c + ig;
  c = cc;
  float ccl = clamp20(cc);
  float eo = __expf(-zo);
  float ec = __expf(-2.0f * ccl);
  float hv = (1.0f - ec) * rcpf((1.0f + eo) * (1.0f + ec));  // sigmoid(zo)*tanh(cc)
  return (_Float16)hv;
}

// A-frag LDS/global layout for a 16x128 fp16 tile:
//   addr(row, col) = (col>>5)*512 + ((col>>3)&3)*128 + row*8 + (col&7)
// Reader (MFMA A-frag, row=l15, k=kt*32+quad*8+j): base = kt*512+(quad*16+l15)*8
// => lane-contiguous 16B blocks, conflict-free ds_read_b128 / coalesced 16B
//    global loads.

// ---------------------------------------------------------------------------
// Fused prep: xpad (A-frag fp16 x), WhhT for both layers, combined bias1.
// ---------------------------------------------------------------------------
__global__ void prep_all(const float* __restrict__ xa, const float* __restrict__ xp,
                         const float* __restrict__ xn,
                         const float* __restrict__ Whh1, const float* __restrict__ Whh2,
                         const float* __restrict__ bih1, const float* __restrict__ bhh1,
                         _Float16* __restrict__ xpad,
                         _Float16* __restrict__ whhT1, _Float16* __restrict__ whhT2,
                         float* __restrict__ b1c) {
  int bid = blockIdx.x, tid = threadIdx.x;
  if (bid < 6144) {                      // xpad: [96 tile][128 t][16 r][8 d]
    int i = bid * 256 + tid;
    int tile = i >> 14, rem = i & 16383;
    int t = rem >> 7, r = (rem >> 3) & 15, d = i & 7;
    int inp = tile >> 5, rloc = (tile & 31) * 16;
    const float* x = (inp == 0) ? xa : ((inp == 1) ? xp : xn);
    xpad[i] = (d < 5) ? (_Float16)x[(rloc + r) * 640 + t * 5 + d] : (_Float16)0.0f;
  } else if (bid < 6656) {               // whhT: [128 k][512 g]
    int i = (bid - 6144) * 256 + tid;
    int which = i >> 16, idx = i & 65535;
    int k = idx >> 9, g = idx & 511;
    const float* src = which ? Whh2 : Whh1;
    (which ? whhT2 : whhT1)[idx] = (_Float16)src[g * HID + k];
  } else {                               // b1c
    int i = (bid - 6656) * 256 + tid;    // 512
    b1c[i] = bih1[i] + bhh1[i];
  }
}

// ---------------------------------------------------------------------------
// LSTM layer 1. 96 WGs x 512. hs1: [96 tile][128 t][2048 halves] A-frag order.
// ---------------------------------------------------------------------------
__global__ __launch_bounds__(512, 2) void lstm1_kernel(
    const _Float16* __restrict__ xpad,   // [96][128][16][8]
    const float* __restrict__ Wih1,      // [512][5]
    const float* __restrict__ b1c,       // [512]
    const _Float16* __restrict__ whhT,   // [128 k][512 g]
    _Float16* __restrict__ hs1,
    float* __restrict__ s1sum, float* __restrict__ s1sq) {
  const int wg = blockIdx.x;             // tile 0..95
  const int inp = wg >> 5;
  const int tid = threadIdx.x;
  const int w = tid >> 6;                // 0..7
  const int lane = tid & 63;
  const int l15 = lane & 15;
  const int quad = lane >> 4;
  const int col = w * 16 + l15;
  const int kb = quad * 8;

  __shared__ _Float16 hb[2][2048];       // double-buffered h, A-frag order, 8 KB
  for (int i = tid; i < 4096; i += 512) ((_Float16*)hb)[i] = (_Float16)0.0f;

  const int rbase = (quad * 16 + l15) * 8;
  const int wbase = (w >> 1) * 512 + ((w & 1) * 2 + (l15 >> 3)) * 128 +
                    quad * 32 + (l15 & 7);

  half8 bh[4][4];                        // [kt][gate]
#pragma unroll
  for (int kt = 0; kt < 4; ++kt)
#pragma unroll
    for (int gt = 0; gt < 4; ++gt) {
      int gcol = gt * 128 + col;
      half8 v;
#pragma unroll
      for (int j = 0; j < 8; ++j) v[j] = whhT[(kt * 32 + kb + j) * NGATE + gcol];
      bh[kt][gt] = v;
    }
  half8 bx[4];                           // Wih1 K=32-padded (quad0, j<5 nonzero)
#pragma unroll
  for (int gt = 0; gt < 4; ++gt) {
    half8 v = {0, 0, 0, 0, 0, 0, 0, 0};
    if (quad == 0) {
#pragma unroll
      for (int j = 0; j < 5; ++j) v[j] = (_Float16)Wih1[(gt * 128 + col) * 5 + j];
    }
    bx[gt] = v;
  }
  f32x4 biasv[4];
#pragma unroll
  for (int gt = 0; gt < 4; ++gt) {
    float b = b1c[gt * 128 + col];
    biasv[gt][0] = b; biasv[gt][1] = b; biasv[gt][2] = b; biasv[gt][3] = b;
  }

  half8 xp = {0, 0, 0, 0, 0, 0, 0, 0};
  if (quad == 0) xp = *(const half8*)&xpad[((size_t)(wg * TS) * 16 + l15) * 8];

  float c[4] = {0, 0, 0, 0};
  float ssum = 0.0f, ssq = 0.0f;
  _Float16* hs1w = hs1 + (size_t)wg * TS * 2048;

  __syncthreads();                       // zero-init visible

  for (int t = 0; t < TS; ++t) {
    // ---- pre-barrier: x-part (prefetched regs, no h dependency) ----
    f32x4 acc[4];
#pragma unroll
    for (int gt = 0; gt < 4; ++gt)
      acc[gt] = __builtin_amdgcn_mfma_f32_16x16x32_f16(xp, bx[gt], biasv[gt], 0, 0, 0);
    if (t + 1 < TS && quad == 0)
      xp = *(const half8*)&xpad[((size_t)(wg * TS + t + 1) * 16 + l15) * 8];
    BAR();                               // h(t-1) LDS writes visible
    if (t > 0) {                         // coalesced h(t-1) -> hs1 (8 B/thread)
      float2 cp = *(const float2*)&hb[t & 1][tid * 4];
      *(float2*)&hs1w[(size_t)(t - 1) * 2048 + tid * 4] = cp;
    }
#pragma unroll
    for (int kt = 0; kt < 4; ++kt) {     // h-part: conflict-free b128 reads
      half8 ah = *(const half8*)&hb[t & 1][kt * 512 + rbase];
#pragma unroll
      for (int gt = 0; gt < 4; ++gt)
        acc[gt] = __builtin_amdgcn_mfma_f32_16x16x32_f16(ah, bh[kt][gt], acc[gt], 0, 0, 0);
    }
    const int wb = (t + 1) & 1;
#pragma unroll
    for (int r = 0; r < 4; ++r) {
      _Float16 hh = lstm_cell(acc[0][r], acc[1][r], acc[2][r], acc[3][r], c[r]);
      float hr = (float)hh;
      ssum += hr; ssq += hr * hr;
      hb[wb][wbase + r * 8] = hh;
    }
  }
  BAR();                                 // h(127) visible
  {
    float2 cp = *(const float2*)&hb[0][tid * 4];
    *(float2*)&hs1w[(size_t)(TS - 1) * 2048 + tid * 4] = cp;
  }
  float s = ssum, q = ssq;
  s += __shfl_xor(s, 16); s += __shfl_xor(s, 32);
  q += __shfl_xor(q, 16); q += __shfl_xor(q, 32);
  if (quad == 0) {
    atomicAdd(&s1sum[inp * HID + col], s);
    atomicAdd(&s1sq[inp * HID + col], q);
  }
}

// ---------------------------------------------------------------------------
// Mid: BN1-folded scaled W2 (fp16) + effective bias2.
// ---------------------------------------------------------------------------
__global__ void mid_kernel(const float* __restrict__ s1sum, const float* __restrict__ s1sq,
                           const float* __restrict__ g1, const float* __restrict__ b1,
                           const float* __restrict__ Wih2,
                           const float* __restrict__ bih2, const float* __restrict__ bhh2,
                           _Float16* __restrict__ w2s, float* __restrict__ bias2eff) {
  int bid = blockIdx.x, tid = threadIdx.x;
  if (bid < 768) {                       // w2s: [3][128 k][512 g]
    int i = bid * 256 + tid;
    int inp = i >> 16, rem = i & 65535, k = rem >> 9, g = rem & 511;
    float m = s1sum[inp * HID + k] * INV_N;
    float v = s1sq[inp * HID + k] * INV_N - m * m;
    float sc = g1[k] * rsqrtf(v + 1e-5f);
    w2s[i] = (_Float16)(sc * Wih2[g * HID + k]);
  } else {                               // bias2eff: [3][512]
    int i = (bid - 768) * 256 + tid;
    int inp = i >> 9, g = i & 511;
    float acc = bih2[g] + bhh2[g];
    for (int h = 0; h < HID; ++h) {
      float m = s1sum[inp * HID + h] * INV_N;
      float v = s1sq[inp * HID + h] * INV_N - m * m;
      float sc = g1[h] * rsqrtf(v + 1e-5f);
      acc += (b1[h] - m * sc) * Wih2[g * HID + h];
    }
    bias2eff[i] = acc;
  }
}

// ---------------------------------------------------------------------------
// LSTM layer 2: fused (folded-BN1) input GEMM + recurrence. 96 WGs x 512.
// ---------------------------------------------------------------------------
__global__ __launch_bounds__(512, 2) void lstm2_kernel(
    const _Float16* __restrict__ hs1,    // [96][128][2048] A-frag order
    const _Float16* __restrict__ whhT2,  // [128 k][512 g]
    const _Float16* __restrict__ w2s,    // [3][128 k][512 g]
    const float* __restrict__ bias2eff,  // [3][512]
    _Float16* __restrict__ h_last,       // [1536][128]
    float* __restrict__ s2sum, float* __restrict__ s2sq) {
  const int wg = blockIdx.x;             // tile 0..95
  const int inp = wg >> 5;
  const int gr0 = wg * 16;
  const int tid = threadIdx.x;
  const int w = tid >> 6;
  const int lane = tid & 63;
  const int l15 = lane & 15;
  const int quad = lane >> 4;
  const int col = w * 16 + l15;
  const int kb = quad * 8;

  __shared__ _Float16 hb[2][2048];
  for (int i = tid; i < 4096; i += 512) ((_Float16*)hb)[i] = (_Float16)0.0f;

  const int rbase = (quad * 16 + l15) * 8;
  const int wbase = (w >> 1) * 512 + ((w & 1) * 2 + (l15 >> 3)) * 128 +
                    quad * 32 + (l15 & 7);

  const _Float16* w2sI = w2s + (size_t)inp * HID * NGATE;
  half8 bh[4][4], bxw[4][4];
#pragma unroll
  for (int kt = 0; kt < 4; ++kt)
#pragma unroll
    for (int gt = 0; gt < 4; ++gt) {
      int gcol = gt * 128 + col;
      half8 vh, vx;
#pragma unroll
      for (int j = 0; j < 8; ++j) {
        vh[j] = whhT2[(kt * 32 + kb + j) * NGATE + gcol];
        vx[j] = w2sI[(kt * 32 + kb + j) * NGATE + gcol];
      }
      bh[kt][gt] = vh;
      bxw[kt][gt] = vx;
    }
  f32x4 biasv[4];
#pragma unroll
  for (int gt = 0; gt < 4; ++gt) {
    float b = bias2eff[inp * NGATE + gt * 128 + col];
    biasv[gt][0] = b; biasv[gt][1] = b; biasv[gt][2] = b; biasv[gt][3] = b;
  }

  const _Float16* hg = hs1 + (size_t)wg * TS * 2048;
  half8 a2A[4], a2B[4];                  // 2-deep prefetch (coalesced 16B loads)
#pragma unroll
  for (int kt = 0; kt < 4; ++kt) {
    a2A[kt] = *(const half8*)&hg[kt * 512 + rbase];
    a2B[kt] = *(const half8*)&hg[(size_t)2048 + kt * 512 + rbase];
  }

  float c[4] = {0, 0, 0, 0};
  float ssum = 0.0f, ssq = 0.0f;

  __syncthreads();                       // zero-init visible

  auto step = [&](int t, half8 (&cur)[4]) {
    f32x4 acc[4];
#pragma unroll
    for (int gt = 0; gt < 4; ++gt)
      acc[gt] = __builtin_amdgcn_mfma_f32_16x16x32_f16(cur[0], bxw[0][gt], biasv[gt], 0, 0, 0);
#pragma unroll
    for (int kt = 1; kt < 4; ++kt)
#pragma unroll
      for (int gt = 0; gt < 4; ++gt)
        acc[gt] = __builtin_amdgcn_mfma_f32_16x16x32_f16(cur[kt], bxw[kt][gt], acc[gt], 0, 0, 0);
    if (t + 2 < TS) {                    // prefetch t+2 into regs just consumed
#pragma unroll
      for (int kt = 0; kt < 4; ++kt)
        cur[kt] = *(const half8*)&hg[(size_t)(t + 2) * 2048 + kt * 512 + rbase];
    }
    BAR();                               // h(t-1) visible; vmcnt untouched
#pragma unroll
    for (int kt = 0; kt < 4; ++kt) {
      half8 ah = *(const half8*)&hb[t & 1][kt * 512 + rbase];
#pragma unroll
      for (int gt = 0; gt < 4; ++gt)
        acc[gt] = __builtin_amdgcn_mfma_f32_16x16x32_f16(ah, bh[kt][gt], acc[gt], 0, 0, 0);
    }
    const int wb = (t + 1) & 1;
#pragma unroll
    for (int r = 0; r < 4; ++r) {
      _Float16 hh = lstm_cell(acc[0][r], acc[1][r], acc[2][r], acc[3][r], c[r]);
      float hr = (float)hh;
      ssum += hr; ssq += hr * hr;
      hb[wb][wbase + r * 8] = hh;
      if (t == TS - 1) h_last[(size_t)(gr0 + quad * 4 + r) * HID + col] = hh;
    }
  };

  for (int t = 0; t < TS; t += 2) {
    step(t, a2A);
    step(t + 1, a2B);
  }

  float s = ssum, q = ssq;
  s += __shfl_xor(s, 16); s += __shfl_xor(s, 32);
  q += __shfl_xor(q, 16); q += __shfl_xor(q, 32);
  if (quad == 0) {
    atomicAdd(&s2sum[inp * HID + col], s);
    atomicAdd(&s2sq[inp * HID + col], q);
  }
}

// ---------------------------------------------------------------------------
// Head: BN2 finalize + FC + L2 normalize. 96 WGs x 16 rows.
// ---------------------------------------------------------------------------
__global__ __launch_bounds__(256, 1) void head_kernel(
    const _Float16* __restrict__ h_last,
    const float* __restrict__ s2sum, const float* __restrict__ s2sq,
    const float* __restrict__ g2, const float* __restrict__ b2,
    const float* __restrict__ fcW, const float* __restrict__ fcb,
    float* __restrict__ out) {
  const int wg = blockIdx.x;
  const int inp = wg >> 5;
  const int gr0 = wg * 16;
  const int tid = threadIdx.x;

  __shared__ float fcwT[128][132];       // fcwT[h][j] = fcW[j][h]
  __shared__ float bnh[16][132];
  __shared__ float s2[128], sh2[128];
  __shared__ float part[16][16];
  __shared__ float inv[16];

  if (tid < 128) {
    float m = s2sum[inp * HID + tid] * INV_N;
    float v = s2sq[inp * HID + tid] * INV_N - m * m;
    float s = g2[tid] * rsqrtf(v + 1e-5f);
    s2[tid] = s; sh2[tid] = b2[tid] - m * s;
  }
  for (int i = tid; i < 16384; i += 256) {
    int j = i >> 7, h = i & 127;
    fcwT[h][j] = fcW[i];
  }
  __syncthreads();
  {
    int row = tid >> 4, c0 = (tid & 15) * 8;
#pragma unroll
    for (int k = 0; k < 8; ++k) {
      int h = c0 + k;
      bnh[row][h] = (float)h_last[(gr0 + row) * HID + h] * s2[h] + sh2[h];
    }
  }
  __syncthreads();
  const int row = tid >> 4, jl = tid & 15;
  float emb[8];
  float sq = 0.0f;
#pragma unroll
  for (int jj = 0; jj < 8; ++jj) {
    int j = jl + jj * 16;
    float acc = fcb[j];
    for (int h = 0; h < HID; ++h) acc += bnh[row][h] * fcwT[h][j];
    emb[jj] = acc; sq += acc * acc;
  }
  part[row][jl] = sq;
  __syncthreads();
  if (tid < 16) {
    float s = 0.0f;
    for (int k = 0; k < 16; ++k) s += part[tid][k];
    float nrm = sqrtf(s);
    inv[tid] = 1.0f / fmaxf(nrm, 1e-12f);
  }
  __syncthreads();
#pragma unroll
  for (int jj = 0; jj < 8; ++jj)
    out[(gr0 + row) * HID + jl + jj * 16] = emb[jj] * inv[row];
}

// ---------------------------------------------------------------------------
extern "C" void kernel_launch(void* const* d_in, const int* in_sizes, int n_in,
                              void* d_out, int out_size, void* d_ws, size_t ws_size,
                              hipStream_t stream) {
  const float* a    = (const float*)d_in[0];
  const float* p    = (const float*)d_in[1];
  const float* nn   = (const float*)d_in[2];
  const float* Wih1 = (const float*)d_in[3];
  const float* Whh1 = (const float*)d_in[4];
  const float* bih1 = (const float*)d_in[5];
  const float* bhh1 = (const float*)d_in[6];
  const float* g1   = (const float*)d_in[7];
  const float* b1   = (const float*)d_in[8];
  const float* Wih2 = (const float*)d_in[9];
  const float* Whh2 = (const float*)d_in[10];
  const float* bih2 = (const float*)d_in[11];
  const float* bhh2 = (const float*)d_in[12];
  const float* g2   = (const float*)d_in[13];
  const float* b2   = (const float*)d_in[14];
  const float* fcW  = (const float*)d_in[15];
  const float* fcb  = (const float*)d_in[16];

  char* ws = (char*)d_ws;
  float* s1sum = (float*)(ws + 0);            // 384 f32
  float* s1sq  = s1sum + 384;
  float* s2sum = s1sum + 768;
  float* s2sq  = s1sum + 1152;                // stats end @6144B
  float* b1c      = (float*)(ws + 6144);      // 512 f32 -> @8192
  float* bias2eff = (float*)(ws + 8192);      // 1536 f32 -> @14336
  _Float16* whhT1 = (_Float16*)(ws + 14336);    // 131072B -> @145408
  _Float16* whhT2 = (_Float16*)(ws + 145408);   // 131072B -> @276480
  _Float16* w2s   = (_Float16*)(ws + 276480);   // 393216B -> @669696
  _Float16* hlast = (_Float16*)(ws + 669696);   // 393216B -> @1062912
  _Float16* xpad  = (_Float16*)(ws + 1062912);  // 3145728B -> @4208640
  _Float16* hs1   = (_Float16*)(ws + 4208640);  // 50331648B -> ~54.5MB total

  hipMemsetAsync(ws, 0, 6144, stream);  // zero BN stats accumulators

  prep_all<<<6658, 256, 0, stream>>>(a, p, nn, Whh1, Whh2, bih1, bhh1,
                                     xpad, whhT1, whhT2, b1c);
  lstm1_kernel<<<96, 512, 0, stream>>>(xpad, Wih1, b1c, whhT1, hs1, s1sum, s1sq);
  mid_kernel<<<774, 256, 0, stream>>>(s1sum, s1sq, g1, b1, Wih2, bih2, bhh2,
                                      w2s, bias2eff);
  lstm2_kernel<<<96, 512, 0, stream>>>(hs1, whhT2, w2s, bias2eff, hlast, s2sum, s2sq);
  head_kernel<<<96, 256, 0, stream>>>(hlast, s2sum, s2sq, g2, b2, fcW, fcb, (float*)d_out);
}